// Round 1
// baseline (2923.378 us; speedup 1.0000x reference)
//
#include <hip/hip_runtime.h>

constexpr int N_NODES = 40000;
constexpr int N_EDGES = 640000;

constexpr float C_INV8     = 0.125f;                  // 1/sqrt(64)
constexpr float C_INV_S32  = 0.17677669529663687f;    // 1/sqrt(32)
constexpr float C_INV_S3   = 0.57735026918962576f;    // 1/sqrt(3)
constexpr float C_INV_S2   = 0.70710678118654752f;    // 1/sqrt(2)
constexpr float C_INV_S96  = 0.10206207261596575f;    // 1/sqrt(96)
constexpr float C_INV_S128 = 0.08838834764831845f;    // 1/sqrt(128)
constexpr float C_INV_NN   = 0.25f;                   // 1/sqrt(16)

__device__ __forceinline__ float bcast(float v, int l) {
  // uniform-index wave broadcast -> SGPR, feeds v_fmac as scalar operand
  return __uint_as_float(__builtin_amdgcn_readlane(__float_as_uint(v), l));
}

// ---------------- K1a: h_s = (s @ lin1_ws) * a / 8 ----------------
__global__ __launch_bounds__(256) void k_node_hs(
    const float* __restrict__ nf, const float* __restrict__ attr,
    const float* __restrict__ w, float* __restrict__ h_s)
{
  int t = blockIdx.x * 256 + threadIdx.x;
  if (t >= N_NODES * 64) return;
  int n = t >> 6, c = t & 63;
  const float* s = nf + (long)n * 160;
  float acc = 0.f;
  #pragma unroll 8
  for (int k = 0; k < 64; ++k) acc = fmaf(s[k], w[k * 64 + c], acc);
  h_s[t] = acc * attr[n] * C_INV8;
}

// ---------------- K1b: h_v[n,d,i] = sum_c v[n,c,i]*lin1_wv[c,d] * a / sqrt(32) ----
__global__ __launch_bounds__(256) void k_node_hv(
    const float* __restrict__ nf, const float* __restrict__ attr,
    const float* __restrict__ w, float* __restrict__ h_v)
{
  int t = blockIdx.x * 256 + threadIdx.x;
  if (t >= N_NODES * 32) return;
  int n = t >> 5, d = t & 31;
  const float* v = nf + (long)n * 160 + 64;
  float a0 = 0.f, a1 = 0.f, a2 = 0.f;
  #pragma unroll 8
  for (int c = 0; c < 32; ++c) {
    float wv = w[c * 32 + d];
    a0 = fmaf(v[3 * c + 0], wv, a0);
    a1 = fmaf(v[3 * c + 1], wv, a1);
    a2 = fmaf(v[3 * c + 2], wv, a2);
  }
  float sc = attr[n] * C_INV_S32;
  h_v[(long)t * 3 + 0] = a0 * sc;
  h_v[(long)t * 3 + 1] = a1 * sc;
  h_v[(long)t * 3 + 2] = a2 * sc;
}

// ---------------- K2: per-edge FC + messages + atomic scatter ----------------
// warp-per-edge; block = 4 warps, each warp handles 64 consecutive edges.
__global__ __launch_bounds__(256) void k_edge(
    const float* __restrict__ escal, const float* __restrict__ eattr,
    const int* __restrict__ esrc, const int* __restrict__ edst,
    const float* __restrict__ fc_w1, const float* __restrict__ fc_w2,
    const float* __restrict__ h_s, const float* __restrict__ h_v,
    float* __restrict__ agg_s, float* __restrict__ agg_v)
{
  __shared__ float W1[64 * 64];    // 16 KB
  __shared__ float W2[64 * 224];   // 57.3 KB
  __shared__ float wbuf[4][224];   // per-warp w scratch, 3.5 KB
  int tid = threadIdx.x;
  for (int i = tid; i < 64 * 64; i += 256) W1[i] = fc_w1[i];
  for (int i = tid; i < 64 * 224; i += 256) W2[i] = fc_w2[i];
  __syncthreads();

  int warp = tid >> 6, lane = tid & 63;
  int c = lane & 31;
  int m4 = (lane < 56) ? (lane * 4) : (55 * 4);
  long ebase = (long)blockIdx.x * 256 + warp * 64;

  for (int j = 0; j < 64; ++j) {
    long e = ebase + j;
    float x = escal[e * 64 + lane];

    // hid[lane] = silu( (x @ W1)/8 )
    float acc = 0.f;
    #pragma unroll
    for (int k = 0; k < 64; ++k) acc = fmaf(bcast(x, k), W1[k * 64 + lane], acc);
    acc *= C_INV8;
    float hid = acc / (1.f + __expf(-acc));

    // w[4m..4m+3] = (hid @ W2)/8, lane m<56
    float4 wa = make_float4(0.f, 0.f, 0.f, 0.f);
    #pragma unroll
    for (int k = 0; k < 64; ++k) {
      float h = bcast(hid, k);
      const float4 wr = *reinterpret_cast<const float4*>(&W2[k * 224 + m4]);
      wa.x = fmaf(h, wr.x, wa.x);
      wa.y = fmaf(h, wr.y, wa.y);
      wa.z = fmaf(h, wr.z, wa.z);
      wa.w = fmaf(h, wr.w, wa.w);
    }
    if (lane < 56) {
      wa.x *= C_INV8; wa.y *= C_INV8; wa.z *= C_INV8; wa.w *= C_INV8;
      *reinterpret_cast<float4*>(&wbuf[warp][m4]) = wa;
    }
    __threadfence_block();  // order wbuf write -> cross-lane wbuf reads (same wave)

    int src = esrc[e], dst = edst[e];
    float ea0 = eattr[e * 4 + 0];
    float e1x = eattr[e * 4 + 1], e1y = eattr[e * 4 + 2], e1z = eattr[e * 4 + 3];
    float es = h_s[(long)src * 64 + lane];
    const float* evp = h_v + (long)src * 96 + 3 * c;
    float ev0 = evp[0], ev1 = evp[1], ev2 = evp[2];

    float w1v = wbuf[warp][lane];
    float w2v = wbuf[warp][64 + lane];
    float w3v = wbuf[warp][128 + c];
    float w4v = wbuf[warp][160 + c];
    float w5v = wbuf[warp][192 + c];

    float* as_ = agg_s + (long)dst * 96;
    float* av_ = agg_v + (long)dst * 384;

    // m_s1 (64 ch)
    unsafeAtomicAdd(&as_[lane], w1v * es * ea0 * C_INV_NN);
    // m_v1 (64 ch x 3)
    float tv = w2v * es * C_INV_NN;
    unsafeAtomicAdd(&av_[3 * lane + 0], tv * e1x);
    unsafeAtomicAdd(&av_[3 * lane + 1], tv * e1y);
    unsafeAtomicAdd(&av_[3 * lane + 2], tv * e1z);
    if (lane < 32) {
      // m_v2 comps 0,2 ; m_v3 comps 0,2
      float b = w3v * ea0 * C_INV_NN;
      unsafeAtomicAdd(&av_[(64 + c) * 3 + 0], b * ev0);
      unsafeAtomicAdd(&av_[(64 + c) * 3 + 2], b * ev2);
      float f = w5v * C_INV_S2 * C_INV_NN;
      unsafeAtomicAdd(&av_[(96 + c) * 3 + 0], f * (ev1 * e1z - ev2 * e1y));
      unsafeAtomicAdd(&av_[(96 + c) * 3 + 2], f * (ev0 * e1y - ev1 * e1x));
    } else {
      // m_s2 ; m_v2 comp 1 ; m_v3 comp 1
      float dotv = ev0 * e1x + ev1 * e1y + ev2 * e1z;
      unsafeAtomicAdd(&as_[64 + c], w4v * dotv * C_INV_S3 * C_INV_NN);
      unsafeAtomicAdd(&av_[(64 + c) * 3 + 1], w3v * ev1 * ea0 * C_INV_NN);
      unsafeAtomicAdd(&av_[(96 + c) * 3 + 1],
                      w5v * (ev2 * e1x - ev0 * e1z) * C_INV_S2 * C_INV_NN);
    }
  }
}

// ---------------- K3a: scalar head ----------------
__global__ __launch_bounds__(256) void k_fin_s(
    const float* __restrict__ nf, const float* __restrict__ attr,
    const float* __restrict__ agg_s, const float* __restrict__ lin2_ws,
    const float* __restrict__ sc_ws, float* __restrict__ out,
    float* __restrict__ gate)
{
  int t = blockIdx.x * 256 + threadIdx.x;
  if (t >= N_NODES * 96) return;
  int n = t / 96, cch = t - n * 96;
  const float* ag = agg_s + (long)n * 96;
  float acc = 0.f;
  #pragma unroll 8
  for (int k = 0; k < 96; ++k) acc = fmaf(ag[k], lin2_ws[k * 96 + cch], acc);
  const float* s = nf + (long)n * 160;
  float acc2 = 0.f;
  #pragma unroll 8
  for (int k = 0; k < 64; ++k) acc2 = fmaf(s[k], sc_ws[k * 96 + cch], acc2);
  float pre = (acc * C_INV_S96 + acc2 * C_INV8) * attr[n];
  if (cch < 64) out[(long)n * 160 + cch] = pre / (1.f + __expf(-pre));  // silu
  else gate[n * 32 + cch - 64] = 1.f / (1.f + __expf(-pre));            // sigmoid
}

// ---------------- K3b: vector head ----------------
__global__ __launch_bounds__(256) void k_fin_v(
    const float* __restrict__ nf, const float* __restrict__ attr,
    const float* __restrict__ agg_v, const float* __restrict__ lin2_wv,
    const float* __restrict__ sc_wv, const float* __restrict__ gate,
    float* __restrict__ out)
{
  int t = blockIdx.x * 256 + threadIdx.x;
  if (t >= N_NODES * 32) return;
  int n = t >> 5, d = t & 31;
  const float* ag = agg_v + (long)n * 384;
  float a0 = 0.f, a1 = 0.f, a2 = 0.f;
  #pragma unroll 4
  for (int cc = 0; cc < 128; ++cc) {
    float wv = lin2_wv[cc * 32 + d];
    a0 = fmaf(ag[3 * cc + 0], wv, a0);
    a1 = fmaf(ag[3 * cc + 1], wv, a1);
    a2 = fmaf(ag[3 * cc + 2], wv, a2);
  }
  const float* v = nf + (long)n * 160 + 64;
  float s0 = 0.f, s1 = 0.f, s2 = 0.f;
  #pragma unroll 8
  for (int cc = 0; cc < 32; ++cc) {
    float wv = sc_wv[cc * 32 + d];
    s0 = fmaf(v[3 * cc + 0], wv, s0);
    s1 = fmaf(v[3 * cc + 1], wv, s1);
    s2 = fmaf(v[3 * cc + 2], wv, s2);
  }
  float a = attr[n];
  float g = gate[t];
  float p0 = (a0 * C_INV_S128 + s0 * C_INV_S32) * a;
  float p1 = (a1 * C_INV_S128 + s1 * C_INV_S32) * a;
  float p2 = (a2 * C_INV_S128 + s2 * C_INV_S32) * a;
  float* o = out + (long)n * 160 + 64 + 3 * d;
  o[0] = g * p0; o[1] = g * p1; o[2] = g * p2;
}

extern "C" void kernel_launch(void* const* d_in, const int* in_sizes, int n_in,
                              void* d_out, int out_size, void* d_ws, size_t ws_size,
                              hipStream_t stream)
{
  const float* nf      = (const float*)d_in[0];
  const float* attr    = (const float*)d_in[1];
  const int*   esrc    = (const int*)d_in[2];
  const int*   edst    = (const int*)d_in[3];
  const float* eattr   = (const float*)d_in[4];
  const float* escal   = (const float*)d_in[5];
  const float* lin1_ws = (const float*)d_in[6];
  const float* lin1_wv = (const float*)d_in[7];
  const float* fc_w1   = (const float*)d_in[8];
  const float* fc_w2   = (const float*)d_in[9];
  const float* sc_ws   = (const float*)d_in[10];
  const float* sc_wv   = (const float*)d_in[11];
  const float* lin2_ws = (const float*)d_in[12];
  const float* lin2_wv = (const float*)d_in[13];
  float* out = (float*)d_out;

  float* ws    = (float*)d_ws;
  float* h_s   = ws;                           // N*64
  float* h_v   = h_s + (size_t)N_NODES * 64;   // N*96
  float* agg_s = h_v + (size_t)N_NODES * 96;   // N*96
  float* agg_v = agg_s + (size_t)N_NODES * 96; // N*384
  float* gate  = h_s;                          // reuse h_s region after K2

  hipMemsetAsync(agg_s, 0, (size_t)N_NODES * (96 + 384) * sizeof(float), stream);
  k_node_hs<<<(N_NODES * 64 + 255) / 256, 256, 0, stream>>>(nf, attr, lin1_ws, h_s);
  k_node_hv<<<(N_NODES * 32 + 255) / 256, 256, 0, stream>>>(nf, attr, lin1_wv, h_v);
  k_edge<<<N_EDGES / 256, 256, 0, stream>>>(escal, eattr, esrc, edst,
                                            fc_w1, fc_w2, h_s, h_v, agg_s, agg_v);
  k_fin_s<<<(N_NODES * 96 + 255) / 256, 256, 0, stream>>>(nf, attr, agg_s, lin2_ws,
                                                          sc_ws, out, gate);
  k_fin_v<<<(N_NODES * 32 + 255) / 256, 256, 0, stream>>>(nf, attr, agg_v, lin2_wv,
                                                          sc_wv, gate, out);
}

// Round 2
// 2879.138 us; speedup vs baseline: 1.0154x; 1.0154x over previous
//
#include <hip/hip_runtime.h>

constexpr int N_NODES = 40000;
constexpr int N_EDGES = 640000;

constexpr float C_INV8     = 0.125f;                  // 1/sqrt(64)
constexpr float C_INV_S32  = 0.17677669529663687f;    // 1/sqrt(32)
constexpr float C_INV_S3   = 0.57735026918962576f;    // 1/sqrt(3)
constexpr float C_INV_S2   = 0.70710678118654752f;    // 1/sqrt(2)
constexpr float C_INV_S96  = 0.10206207261596575f;    // 1/sqrt(96)
constexpr float C_INV_S128 = 0.08838834764831845f;    // 1/sqrt(128)
constexpr float C_INV_NN   = 0.25f;                   // 1/sqrt(16)

typedef __attribute__((ext_vector_type(8))) short short8;
typedef __attribute__((ext_vector_type(4))) float f32x4;

__device__ __forceinline__ unsigned short f2bf(float x) {
  union { float f; unsigned int u; } v; v.f = x;
  unsigned int r = v.u + 0x7fffu + ((v.u >> 16) & 1u);  // RNE
  return (unsigned short)(r >> 16);
}
__device__ __forceinline__ float bf2f(unsigned short h) {
  return __uint_as_float(((unsigned int)h) << 16);
}

// ---------------- prep: transpose weights to bf16 [col][k] ----------------
__global__ __launch_bounds__(256) void k_prep(
    const float* __restrict__ fc_w1, const float* __restrict__ fc_w2,
    unsigned short* __restrict__ w1t, unsigned short* __restrict__ w2t)
{
  int t = blockIdx.x * 256 + threadIdx.x;
  if (t < 64 * 64) {
    int c = t >> 6, k = t & 63;
    w1t[c * 64 + k] = f2bf(fc_w1[k * 64 + c]);
  }
  int u = t - 64 * 64;
  if (u >= 0 && u < 224 * 64) {
    int c = u >> 6, k = u & 63;
    w2t[c * 64 + k] = f2bf(fc_w2[k * 224 + c]);
  }
}

// ---------------- K1a: h_s = (s @ lin1_ws) * a / 8 ----------------
__global__ __launch_bounds__(256) void k_node_hs(
    const float* __restrict__ nf, const float* __restrict__ attr,
    const float* __restrict__ w, float* __restrict__ h_s)
{
  int t = blockIdx.x * 256 + threadIdx.x;
  if (t >= N_NODES * 64) return;
  int n = t >> 6, c = t & 63;
  const float* s = nf + (long)n * 160;
  float acc = 0.f;
  #pragma unroll 8
  for (int k = 0; k < 64; ++k) acc = fmaf(s[k], w[k * 64 + c], acc);
  h_s[t] = acc * attr[n] * C_INV8;
}

// ---------------- K1b: h_v ----------------
__global__ __launch_bounds__(256) void k_node_hv(
    const float* __restrict__ nf, const float* __restrict__ attr,
    const float* __restrict__ w, float* __restrict__ h_v)
{
  int t = blockIdx.x * 256 + threadIdx.x;
  if (t >= N_NODES * 32) return;
  int n = t >> 5, d = t & 31;
  const float* v = nf + (long)n * 160 + 64;
  float a0 = 0.f, a1 = 0.f, a2 = 0.f;
  #pragma unroll 8
  for (int c = 0; c < 32; ++c) {
    float wv = w[c * 32 + d];
    a0 = fmaf(v[3 * c + 0], wv, a0);
    a1 = fmaf(v[3 * c + 1], wv, a1);
    a2 = fmaf(v[3 * c + 2], wv, a2);
  }
  float sc = attr[n] * C_INV_S32;
  h_v[(long)t * 3 + 0] = a0 * sc;
  h_v[(long)t * 3 + 1] = a1 * sc;
  h_v[(long)t * 3 + 2] = a2 * sc;
}

// ---------------- K2: fused MFMA FC + messages + atomic scatter ----------------
// block = 4 waves, 64 edges; wave w owns edges [16w,16w+16) of the block tile.
__global__ __launch_bounds__(256, 4) void k_edge(
    const float* __restrict__ escal, const float* __restrict__ eattr,
    const int* __restrict__ esrc, const int* __restrict__ edst,
    const unsigned short* __restrict__ w1t, const unsigned short* __restrict__ w2t,
    const float* __restrict__ h_s, const float* __restrict__ h_v,
    float* __restrict__ agg_s, float* __restrict__ agg_v)
{
  __shared__ unsigned short hid_lds[64 * 72];   // 9.2 KB, pad 64->72
  __shared__ unsigned short w_lds[64 * 232];    // 29.7 KB, pad 224->232
  int tid = threadIdx.x, warp = tid >> 6, lane = tid & 63;
  int lr = lane & 15, lg = lane >> 4;           // frag row / k-group
  long e0 = (long)blockIdx.x * 64;
  int r0 = warp * 16;

  // ---- layer1: hid = silu((escal @ W1)/8), 16 edges x 64 per wave ----
  f32x4 acc[4] = {};
  #pragma unroll
  for (int ks = 0; ks < 2; ++ks) {
    const float* ap = escal + (e0 + r0 + lr) * 64 + ks * 32 + lg * 8;
    float4 a01 = *reinterpret_cast<const float4*>(ap);
    float4 a23 = *reinterpret_cast<const float4*>(ap + 4);
    short8 af;
    af[0] = (short)f2bf(a01.x); af[1] = (short)f2bf(a01.y);
    af[2] = (short)f2bf(a01.z); af[3] = (short)f2bf(a01.w);
    af[4] = (short)f2bf(a23.x); af[5] = (short)f2bf(a23.y);
    af[6] = (short)f2bf(a23.z); af[7] = (short)f2bf(a23.w);
    #pragma unroll
    for (int nt = 0; nt < 4; ++nt) {
      short8 bf = *reinterpret_cast<const short8*>(w1t + (nt * 16 + lr) * 64 + ks * 32 + lg * 8);
      acc[nt] = __builtin_amdgcn_mfma_f32_16x16x32_bf16(af, bf, acc[nt], 0, 0, 0);
    }
  }
  #pragma unroll
  for (int nt = 0; nt < 4; ++nt)
    #pragma unroll
    for (int r = 0; r < 4; ++r) {
      float x = acc[nt][r] * C_INV8;
      float h = x / (1.f + __expf(-x));
      hid_lds[(r0 + lg * 4 + r) * 72 + nt * 16 + lr] = f2bf(h);
    }
  __syncthreads();

  // ---- layer2: w = (hid @ W2)/8, 16 edges x 224 per wave ----
  f32x4 acc2[14] = {};
  #pragma unroll
  for (int ks = 0; ks < 2; ++ks) {
    short8 af = *reinterpret_cast<const short8*>(hid_lds + (r0 + lr) * 72 + ks * 32 + lg * 8);
    #pragma unroll
    for (int nt = 0; nt < 14; ++nt) {
      short8 bf = *reinterpret_cast<const short8*>(w2t + (nt * 16 + lr) * 64 + ks * 32 + lg * 8);
      acc2[nt] = __builtin_amdgcn_mfma_f32_16x16x32_bf16(af, bf, acc2[nt], 0, 0, 0);
    }
  }
  #pragma unroll
  for (int nt = 0; nt < 14; ++nt)
    #pragma unroll
    for (int r = 0; r < 4; ++r)
      w_lds[(r0 + lg * 4 + r) * 232 + nt * 16 + lr] = f2bf(acc2[nt][r] * C_INV8);
  __syncthreads();

  // ---- messages + atomic scatter: warp's own 16 edges ----
  int c = lane & 31;
  for (int j = 0; j < 16; ++j) {
    long e = e0 + r0 + j;
    const unsigned short* wrow = w_lds + (r0 + j) * 232;
    float w1v = bf2f(wrow[lane]);
    float w2v = bf2f(wrow[64 + lane]);
    float w3v = bf2f(wrow[128 + c]);
    float w4v = bf2f(wrow[160 + c]);
    float w5v = bf2f(wrow[192 + c]);

    int src = esrc[e], dst = edst[e];
    float ea0 = eattr[e * 4 + 0];
    float e1x = eattr[e * 4 + 1], e1y = eattr[e * 4 + 2], e1z = eattr[e * 4 + 3];
    float es = h_s[(long)src * 64 + lane];
    const float* evp = h_v + (long)src * 96 + 3 * c;
    float ev0 = evp[0], ev1 = evp[1], ev2 = evp[2];

    float* as_ = agg_s + (long)dst * 96;
    float* av_ = agg_v + (long)dst * 384;

    unsafeAtomicAdd(&as_[lane], w1v * es * ea0 * C_INV_NN);
    float tv = w2v * es * C_INV_NN;
    unsafeAtomicAdd(&av_[3 * lane + 0], tv * e1x);
    unsafeAtomicAdd(&av_[3 * lane + 1], tv * e1y);
    unsafeAtomicAdd(&av_[3 * lane + 2], tv * e1z);
    if (lane < 32) {
      float b = w3v * ea0 * C_INV_NN;
      unsafeAtomicAdd(&av_[(64 + c) * 3 + 0], b * ev0);
      unsafeAtomicAdd(&av_[(64 + c) * 3 + 2], b * ev2);
      float f = w5v * C_INV_S2 * C_INV_NN;
      unsafeAtomicAdd(&av_[(96 + c) * 3 + 0], f * (ev1 * e1z - ev2 * e1y));
      unsafeAtomicAdd(&av_[(96 + c) * 3 + 2], f * (ev0 * e1y - ev1 * e1x));
    } else {
      float dotv = ev0 * e1x + ev1 * e1y + ev2 * e1z;
      unsafeAtomicAdd(&as_[64 + c], w4v * dotv * C_INV_S3 * C_INV_NN);
      unsafeAtomicAdd(&av_[(64 + c) * 3 + 1], w3v * ev1 * ea0 * C_INV_NN);
      unsafeAtomicAdd(&av_[(96 + c) * 3 + 1],
                      w5v * (ev2 * e1x - ev0 * e1z) * C_INV_S2 * C_INV_NN);
    }
  }
}

// ---------------- K3a: scalar head ----------------
__global__ __launch_bounds__(256) void k_fin_s(
    const float* __restrict__ nf, const float* __restrict__ attr,
    const float* __restrict__ agg_s, const float* __restrict__ lin2_ws,
    const float* __restrict__ sc_ws, float* __restrict__ out,
    float* __restrict__ gate)
{
  int t = blockIdx.x * 256 + threadIdx.x;
  if (t >= N_NODES * 96) return;
  int n = t / 96, cch = t - n * 96;
  const float* ag = agg_s + (long)n * 96;
  float acc = 0.f;
  #pragma unroll 8
  for (int k = 0; k < 96; ++k) acc = fmaf(ag[k], lin2_ws[k * 96 + cch], acc);
  const float* s = nf + (long)n * 160;
  float acc2 = 0.f;
  #pragma unroll 8
  for (int k = 0; k < 64; ++k) acc2 = fmaf(s[k], sc_ws[k * 96 + cch], acc2);
  float pre = (acc * C_INV_S96 + acc2 * C_INV8) * attr[n];
  if (cch < 64) out[(long)n * 160 + cch] = pre / (1.f + __expf(-pre));
  else gate[n * 32 + cch - 64] = 1.f / (1.f + __expf(-pre));
}

// ---------------- K3b: vector head ----------------
__global__ __launch_bounds__(256) void k_fin_v(
    const float* __restrict__ nf, const float* __restrict__ attr,
    const float* __restrict__ agg_v, const float* __restrict__ lin2_wv,
    const float* __restrict__ sc_wv, const float* __restrict__ gate,
    float* __restrict__ out)
{
  int t = blockIdx.x * 256 + threadIdx.x;
  if (t >= N_NODES * 32) return;
  int n = t >> 5, d = t & 31;
  const float* ag = agg_v + (long)n * 384;
  float a0 = 0.f, a1 = 0.f, a2 = 0.f;
  #pragma unroll 4
  for (int cc = 0; cc < 128; ++cc) {
    float wv = lin2_wv[cc * 32 + d];
    a0 = fmaf(ag[3 * cc + 0], wv, a0);
    a1 = fmaf(ag[3 * cc + 1], wv, a1);
    a2 = fmaf(ag[3 * cc + 2], wv, a2);
  }
  const float* v = nf + (long)n * 160 + 64;
  float s0 = 0.f, s1 = 0.f, s2 = 0.f;
  #pragma unroll 8
  for (int cc = 0; cc < 32; ++cc) {
    float wv = sc_wv[cc * 32 + d];
    s0 = fmaf(v[3 * cc + 0], wv, s0);
    s1 = fmaf(v[3 * cc + 1], wv, s1);
    s2 = fmaf(v[3 * cc + 2], wv, s2);
  }
  float a = attr[n];
  float g = gate[t];
  float p0 = (a0 * C_INV_S128 + s0 * C_INV_S32) * a;
  float p1 = (a1 * C_INV_S128 + s1 * C_INV_S32) * a;
  float p2 = (a2 * C_INV_S128 + s2 * C_INV_S32) * a;
  float* o = out + (long)n * 160 + 64 + 3 * d;
  o[0] = g * p0; o[1] = g * p1; o[2] = g * p2;
}

extern "C" void kernel_launch(void* const* d_in, const int* in_sizes, int n_in,
                              void* d_out, int out_size, void* d_ws, size_t ws_size,
                              hipStream_t stream)
{
  const float* nf      = (const float*)d_in[0];
  const float* attr    = (const float*)d_in[1];
  const int*   esrc    = (const int*)d_in[2];
  const int*   edst    = (const int*)d_in[3];
  const float* eattr   = (const float*)d_in[4];
  const float* escal   = (const float*)d_in[5];
  const float* lin1_ws = (const float*)d_in[6];
  const float* lin1_wv = (const float*)d_in[7];
  const float* fc_w1   = (const float*)d_in[8];
  const float* fc_w2   = (const float*)d_in[9];
  const float* sc_ws   = (const float*)d_in[10];
  const float* sc_wv   = (const float*)d_in[11];
  const float* lin2_ws = (const float*)d_in[12];
  const float* lin2_wv = (const float*)d_in[13];
  float* out = (float*)d_out;

  float* ws    = (float*)d_ws;
  float* h_s   = ws;                           // N*64
  float* h_v   = h_s + (size_t)N_NODES * 64;   // N*96
  float* agg_s = h_v + (size_t)N_NODES * 96;   // N*96
  float* agg_v = agg_s + (size_t)N_NODES * 96; // N*384
  unsigned short* w1t = (unsigned short*)(agg_v + (size_t)N_NODES * 384); // 64*64
  unsigned short* w2t = w1t + 64 * 64;                                    // 224*64
  float* gate  = h_s;                          // reuse h_s region after K2

  hipMemsetAsync(agg_s, 0, (size_t)N_NODES * (96 + 384) * sizeof(float), stream);
  k_prep<<<(64 * 64 + 224 * 64 + 255) / 256, 256, 0, stream>>>(fc_w1, fc_w2, w1t, w2t);
  k_node_hs<<<(N_NODES * 64 + 255) / 256, 256, 0, stream>>>(nf, attr, lin1_ws, h_s);
  k_node_hv<<<(N_NODES * 32 + 255) / 256, 256, 0, stream>>>(nf, attr, lin1_wv, h_v);
  k_edge<<<N_EDGES / 64, 256, 0, stream>>>(escal, eattr, esrc, edst,
                                           w1t, w2t, h_s, h_v, agg_s, agg_v);
  k_fin_s<<<(N_NODES * 96 + 255) / 256, 256, 0, stream>>>(nf, attr, agg_s, lin2_ws,
                                                          sc_ws, out, gate);
  k_fin_v<<<(N_NODES * 32 + 255) / 256, 256, 0, stream>>>(nf, attr, agg_v, lin2_wv,
                                                          sc_wv, gate, out);
}

// Round 4
// 614.309 us; speedup vs baseline: 4.7588x; 4.6868x over previous
//
#include <hip/hip_runtime.h>

constexpr int N_NODES = 40000;
constexpr int N_EDGES = 640000;

constexpr float C_INV8     = 0.125f;                  // 1/sqrt(64)
constexpr float C_INV_S32  = 0.17677669529663687f;    // 1/sqrt(32)
constexpr float C_INV_S3   = 0.57735026918962576f;    // 1/sqrt(3)
constexpr float C_INV_S2   = 0.70710678118654752f;    // 1/sqrt(2)
constexpr float C_INV_S96  = 0.10206207261596575f;    // 1/sqrt(96)
constexpr float C_INV_S128 = 0.08838834764831845f;    // 1/sqrt(128)
constexpr float C_INV_NN   = 0.25f;                   // 1/sqrt(16)

typedef __attribute__((ext_vector_type(8))) short short8;
typedef __attribute__((ext_vector_type(4))) float f32x4;

__device__ __forceinline__ unsigned short f2bf(float x) {
  union { float f; unsigned int u; } v; v.f = x;
  unsigned int r = v.u + 0x7fffu + ((v.u >> 16) & 1u);  // RNE
  return (unsigned short)(r >> 16);
}
__device__ __forceinline__ float bf2f(unsigned short h) {
  return __uint_as_float(((unsigned int)h) << 16);
}

// ---- prep: bf16-transpose fc_w1, fc_w2, lin2_ws, lin2_wv to [col][k] ----
__global__ __launch_bounds__(256) void k_prep(
    const float* __restrict__ fc_w1, const float* __restrict__ fc_w2,
    const float* __restrict__ lin2_ws, const float* __restrict__ lin2_wv,
    unsigned short* __restrict__ w1t, unsigned short* __restrict__ w2t,
    unsigned short* __restrict__ wst, unsigned short* __restrict__ wvt)
{
  int t = blockIdx.x * 256 + threadIdx.x;
  if (t < 4096) {                       // w1t: 64x64
    int c = t >> 6, k = t & 63;
    w1t[c * 64 + k] = f2bf(fc_w1[k * 64 + c]);
  } else if (t < 4096 + 14336) {        // w2t: 224x64
    int u = t - 4096; int c = u >> 6, k = u & 63;
    w2t[c * 64 + k] = f2bf(fc_w2[k * 224 + c]);
  } else if (t < 18432 + 9216) {        // wst: 96x96
    int u = t - 18432; int c = u / 96, k = u - c * 96;
    wst[c * 96 + k] = f2bf(lin2_ws[k * 96 + c]);
  } else if (t < 27648 + 4096) {        // wvt: 32x128
    int u = t - 27648; int d = u >> 7, k = u & 127;
    wvt[d * 128 + k] = f2bf(lin2_wv[k * 32 + d]);
  }
}

// ---------------- K1a: h_s = (s @ lin1_ws) * a / 8 ----------------
__global__ __launch_bounds__(256) void k_node_hs(
    const float* __restrict__ nf, const float* __restrict__ attr,
    const float* __restrict__ w, float* __restrict__ h_s)
{
  int t = blockIdx.x * 256 + threadIdx.x;
  if (t >= N_NODES * 64) return;
  int n = t >> 6, c = t & 63;
  const float* s = nf + (long)n * 160;
  float acc = 0.f;
  #pragma unroll 8
  for (int k = 0; k < 64; ++k) acc = fmaf(s[k], w[k * 64 + c], acc);
  h_s[t] = acc * attr[n] * C_INV8;
}

// ---------------- K1b: h_v ----------------
__global__ __launch_bounds__(256) void k_node_hv(
    const float* __restrict__ nf, const float* __restrict__ attr,
    const float* __restrict__ w, float* __restrict__ h_v)
{
  int t = blockIdx.x * 256 + threadIdx.x;
  if (t >= N_NODES * 32) return;
  int n = t >> 5, d = t & 31;
  const float* v = nf + (long)n * 160 + 64;
  float a0 = 0.f, a1 = 0.f, a2 = 0.f;
  #pragma unroll 8
  for (int c = 0; c < 32; ++c) {
    float wv = w[c * 32 + d];
    a0 = fmaf(v[3 * c + 0], wv, a0);
    a1 = fmaf(v[3 * c + 1], wv, a1);
    a2 = fmaf(v[3 * c + 2], wv, a2);
  }
  float sc = attr[n] * C_INV_S32;
  h_v[(long)t * 3 + 0] = a0 * sc;
  h_v[(long)t * 3 + 1] = a1 * sc;
  h_v[(long)t * 3 + 2] = a2 * sc;
}

// ---- K2: fused FC(MFMA) + messages + per-edge lin2(MFMA) + atomic scatter ----
// block = 4 waves, 64 edges; wave w owns edges [16w,16w+16).
__global__ __launch_bounds__(256, 2) void k_edge(
    const float* __restrict__ escal, const float* __restrict__ eattr,
    const int* __restrict__ esrc, const int* __restrict__ edst,
    const unsigned short* __restrict__ w1t, const unsigned short* __restrict__ w2t,
    const unsigned short* __restrict__ wst, const unsigned short* __restrict__ wvt,
    const float* __restrict__ h_s, const float* __restrict__ h_v,
    float* __restrict__ agg_s, float* __restrict__ agg_v)
{
  __shared__ unsigned short hid_lds[64 * 72];   // 9.2 KB
  __shared__ unsigned short w_lds[64 * 232];    // 29.7 KB
  int tid = threadIdx.x, warp = tid >> 6, lane = tid & 63;
  int lr = lane & 15, lg = lane >> 4;
  long e0 = (long)blockIdx.x * 64;
  int r0 = warp * 16;

  // ---- layer1: hid = silu((escal @ W1)/8) ----
  f32x4 acc[4] = {};
  #pragma unroll
  for (int ks = 0; ks < 2; ++ks) {
    const float* ap = escal + (e0 + r0 + lr) * 64 + ks * 32 + lg * 8;
    float4 a01 = *reinterpret_cast<const float4*>(ap);
    float4 a23 = *reinterpret_cast<const float4*>(ap + 4);
    short8 af;
    af[0] = (short)f2bf(a01.x); af[1] = (short)f2bf(a01.y);
    af[2] = (short)f2bf(a01.z); af[3] = (short)f2bf(a01.w);
    af[4] = (short)f2bf(a23.x); af[5] = (short)f2bf(a23.y);
    af[6] = (short)f2bf(a23.z); af[7] = (short)f2bf(a23.w);
    #pragma unroll
    for (int nt = 0; nt < 4; ++nt) {
      short8 bf = *reinterpret_cast<const short8*>(w1t + (nt * 16 + lr) * 64 + ks * 32 + lg * 8);
      acc[nt] = __builtin_amdgcn_mfma_f32_16x16x32_bf16(af, bf, acc[nt], 0, 0, 0);
    }
  }
  #pragma unroll
  for (int nt = 0; nt < 4; ++nt)
    #pragma unroll
    for (int r = 0; r < 4; ++r) {
      float x = acc[nt][r] * C_INV8;
      float h = x / (1.f + __expf(-x));
      hid_lds[(r0 + lg * 4 + r) * 72 + nt * 16 + lr] = f2bf(h);
    }
  __syncthreads();

  // ---- layer2: w = (hid @ W2)/8 -> w_lds ----
  f32x4 acc2[14] = {};
  #pragma unroll
  for (int ks = 0; ks < 2; ++ks) {
    short8 af = *reinterpret_cast<const short8*>(hid_lds + (r0 + lr) * 72 + ks * 32 + lg * 8);
    #pragma unroll
    for (int nt = 0; nt < 14; ++nt) {
      short8 bf = *reinterpret_cast<const short8*>(w2t + (nt * 16 + lr) * 64 + ks * 32 + lg * 8);
      acc2[nt] = __builtin_amdgcn_mfma_f32_16x16x32_bf16(af, bf, acc2[nt], 0, 0, 0);
    }
  }
  #pragma unroll
  for (int nt = 0; nt < 14; ++nt)
    #pragma unroll
    for (int r = 0; r < 4; ++r)
      w_lds[(r0 + lg * 4 + r) * 232 + nt * 16 + lr] = f2bf(acc2[nt][r] * C_INV8);
  __syncthreads();

  // ---- per-lane message ingredients for its own edge (row r0+lr) ----
  long eM = e0 + r0 + lr;
  int srcM = esrc[eM];
  float ea0 = eattr[eM * 4 + 0];
  float e1x = eattr[eM * 4 + 1], e1y = eattr[eM * 4 + 2], e1z = eattr[eM * 4 + 3];

  float esv[16];  // h_s[src] chans [lg*8,+8) and [32+lg*8,+8)
  {
    const float* hsr = h_s + (long)srcM * 64;
    *reinterpret_cast<float4*>(&esv[0])  = *reinterpret_cast<const float4*>(hsr + lg * 8);
    *reinterpret_cast<float4*>(&esv[4])  = *reinterpret_cast<const float4*>(hsr + lg * 8 + 4);
    *reinterpret_cast<float4*>(&esv[8])  = *reinterpret_cast<const float4*>(hsr + 32 + lg * 8);
    *reinterpret_cast<float4*>(&esv[12]) = *reinterpret_cast<const float4*>(hsr + 32 + lg * 8 + 4);
  }
  float evv[24];  // h_v[src] chans [lg*8,+8) x 3 comps, contiguous
  {
    const float* hvr = h_v + (long)srcM * 96 + lg * 24;
    #pragma unroll
    for (int q = 0; q < 6; ++q)
      *reinterpret_cast<float4*>(&evv[4 * q]) = *reinterpret_cast<const float4*>(hvr + 4 * q);
  }
  const unsigned short* wrow = w_lds + (r0 + lr) * 232;   // FIX: was lr*232
  short8 w1a = *reinterpret_cast<const short8*>(wrow + lg * 8);
  short8 w1b = *reinterpret_cast<const short8*>(wrow + 32 + lg * 8);
  short8 w2a = *reinterpret_cast<const short8*>(wrow + 64 + lg * 8);
  short8 w2b = *reinterpret_cast<const short8*>(wrow + 96 + lg * 8);
  short8 w3s = *reinterpret_cast<const short8*>(wrow + 128 + lg * 8);
  short8 w4s = *reinterpret_cast<const short8*>(wrow + 160 + lg * 8);
  short8 w5s = *reinterpret_cast<const short8*>(wrow + 192 + lg * 8);

  // ---- S-GEMM: [16 edges x 96 mid_s] @ wst -> 16x96 ----
  f32x4 accS[6] = {};
  {
    short8 aS;
    #pragma unroll
    for (int j = 0; j < 8; ++j) aS[j] = (short)f2bf(bf2f((unsigned short)w1a[j]) * esv[j] * ea0);
    #pragma unroll
    for (int nt = 0; nt < 6; ++nt) {
      short8 b = *reinterpret_cast<const short8*>(wst + (nt * 16 + lr) * 96 + lg * 8);
      accS[nt] = __builtin_amdgcn_mfma_f32_16x16x32_bf16(aS, b, accS[nt], 0, 0, 0);
    }
    #pragma unroll
    for (int j = 0; j < 8; ++j) aS[j] = (short)f2bf(bf2f((unsigned short)w1b[j]) * esv[8 + j] * ea0);
    #pragma unroll
    for (int nt = 0; nt < 6; ++nt) {
      short8 b = *reinterpret_cast<const short8*>(wst + (nt * 16 + lr) * 96 + 32 + lg * 8);
      accS[nt] = __builtin_amdgcn_mfma_f32_16x16x32_bf16(aS, b, accS[nt], 0, 0, 0);
    }
    #pragma unroll
    for (int j = 0; j < 8; ++j) {
      float dot = evv[3 * j] * e1x + evv[3 * j + 1] * e1y + evv[3 * j + 2] * e1z;
      aS[j] = (short)f2bf(bf2f((unsigned short)w4s[j]) * dot * C_INV_S3);
    }
    #pragma unroll
    for (int nt = 0; nt < 6; ++nt) {
      short8 b = *reinterpret_cast<const short8*>(wst + (nt * 16 + lr) * 96 + 64 + lg * 8);
      accS[nt] = __builtin_amdgcn_mfma_f32_16x16x32_bf16(aS, b, accS[nt], 0, 0, 0);
    }
  }

  // ---- V-GEMMs: per comp i, [16 x 128 mid_v_i] @ wvt -> 16x32 ----
  f32x4 accV[6] = {};  // [i*2+nt]
  #pragma unroll
  for (int i = 0; i < 3; ++i) {
    float e1i = (i == 0) ? e1x : (i == 1) ? e1y : e1z;
    short8 aV;
    #pragma unroll
    for (int j = 0; j < 8; ++j) aV[j] = (short)f2bf(bf2f((unsigned short)w2a[j]) * esv[j] * e1i);
    #pragma unroll
    for (int nt = 0; nt < 2; ++nt) {
      short8 b = *reinterpret_cast<const short8*>(wvt + (nt * 16 + lr) * 128 + lg * 8);
      accV[i * 2 + nt] = __builtin_amdgcn_mfma_f32_16x16x32_bf16(aV, b, accV[i * 2 + nt], 0, 0, 0);
    }
    #pragma unroll
    for (int j = 0; j < 8; ++j) aV[j] = (short)f2bf(bf2f((unsigned short)w2b[j]) * esv[8 + j] * e1i);
    #pragma unroll
    for (int nt = 0; nt < 2; ++nt) {
      short8 b = *reinterpret_cast<const short8*>(wvt + (nt * 16 + lr) * 128 + 32 + lg * 8);
      accV[i * 2 + nt] = __builtin_amdgcn_mfma_f32_16x16x32_bf16(aV, b, accV[i * 2 + nt], 0, 0, 0);
    }
    #pragma unroll
    for (int j = 0; j < 8; ++j) aV[j] = (short)f2bf(bf2f((unsigned short)w3s[j]) * evv[3 * j + i] * ea0);
    #pragma unroll
    for (int nt = 0; nt < 2; ++nt) {
      short8 b = *reinterpret_cast<const short8*>(wvt + (nt * 16 + lr) * 128 + 64 + lg * 8);
      accV[i * 2 + nt] = __builtin_amdgcn_mfma_f32_16x16x32_bf16(aV, b, accV[i * 2 + nt], 0, 0, 0);
    }
    #pragma unroll
    for (int j = 0; j < 8; ++j) {
      float ex = evv[3 * j], ey = evv[3 * j + 1], ez = evv[3 * j + 2];
      float cr = (i == 0) ? (ey * e1z - ez * e1y)
               : (i == 1) ? (ez * e1x - ex * e1z)
                          : (ex * e1y - ey * e1x);
      aV[j] = (short)f2bf(bf2f((unsigned short)w5s[j]) * cr * C_INV_S2);
    }
    #pragma unroll
    for (int nt = 0; nt < 2; ++nt) {
      short8 b = *reinterpret_cast<const short8*>(wvt + (nt * 16 + lr) * 128 + 96 + lg * 8);
      accV[i * 2 + nt] = __builtin_amdgcn_mfma_f32_16x16x32_bf16(aV, b, accV[i * 2 + nt], 0, 0, 0);
    }
  }

  // ---- atomic scatter: 192 floats/edge (o_s 96 + o_v 96) ----
  #pragma unroll
  for (int r = 0; r < 4; ++r) {
    int dstR = edst[e0 + r0 + lg * 4 + r];
    float* asp = agg_s + (long)dstR * 96;
    #pragma unroll
    for (int nt = 0; nt < 6; ++nt) unsafeAtomicAdd(&asp[nt * 16 + lr], accS[nt][r]);
    float* avp = agg_v + (long)dstR * 96;   // layout [n][i][d]
    #pragma unroll
    for (int q = 0; q < 6; ++q) {
      int i = q >> 1, nt = q & 1;
      unsafeAtomicAdd(&avp[i * 32 + nt * 16 + lr], accV[q][r]);
    }
  }
}

// ---------------- K3a: scalar head ----------------
__global__ __launch_bounds__(256) void k_fin_s(
    const float* __restrict__ nf, const float* __restrict__ attr,
    const float* __restrict__ agg_s, const float* __restrict__ sc_ws,
    float* __restrict__ out, float* __restrict__ gate)
{
  int t = blockIdx.x * 256 + threadIdx.x;
  if (t >= N_NODES * 96) return;
  int n = t / 96, cch = t - n * 96;
  const float* s = nf + (long)n * 160;
  float acc2 = 0.f;
  #pragma unroll 8
  for (int k = 0; k < 64; ++k) acc2 = fmaf(s[k], sc_ws[k * 96 + cch], acc2);
  float pre = (agg_s[t] * (C_INV_NN * C_INV_S96) + acc2 * C_INV8) * attr[n];
  if (cch < 64) out[(long)n * 160 + cch] = pre / (1.f + __expf(-pre));
  else gate[n * 32 + cch - 64] = 1.f / (1.f + __expf(-pre));
}

// ---------------- K3b: vector head ----------------
__global__ __launch_bounds__(256) void k_fin_v(
    const float* __restrict__ nf, const float* __restrict__ attr,
    const float* __restrict__ agg_v, const float* __restrict__ sc_wv,
    const float* __restrict__ gate, float* __restrict__ out)
{
  int t = blockIdx.x * 256 + threadIdx.x;
  if (t >= N_NODES * 32) return;
  int n = t >> 5, d = t & 31;
  const float* v = nf + (long)n * 160 + 64;
  float s0 = 0.f, s1 = 0.f, s2 = 0.f;
  #pragma unroll 8
  for (int cc = 0; cc < 32; ++cc) {
    float wv = sc_wv[cc * 32 + d];
    s0 = fmaf(v[3 * cc + 0], wv, s0);
    s1 = fmaf(v[3 * cc + 1], wv, s1);
    s2 = fmaf(v[3 * cc + 2], wv, s2);
  }
  const float* ag = agg_v + (long)n * 96;
  float a = attr[n];
  float g = gate[t];
  float p0 = (ag[0 * 32 + d] * (C_INV_NN * C_INV_S128) + s0 * C_INV_S32) * a;
  float p1 = (ag[1 * 32 + d] * (C_INV_NN * C_INV_S128) + s1 * C_INV_S32) * a;
  float p2 = (ag[2 * 32 + d] * (C_INV_NN * C_INV_S128) + s2 * C_INV_S32) * a;
  float* o = out + (long)n * 160 + 64 + 3 * d;
  o[0] = g * p0; o[1] = g * p1; o[2] = g * p2;
}

extern "C" void kernel_launch(void* const* d_in, const int* in_sizes, int n_in,
                              void* d_out, int out_size, void* d_ws, size_t ws_size,
                              hipStream_t stream)
{
  const float* nf      = (const float*)d_in[0];
  const float* attr    = (const float*)d_in[1];
  const int*   esrc    = (const int*)d_in[2];
  const int*   edst    = (const int*)d_in[3];
  const float* eattr   = (const float*)d_in[4];
  const float* escal   = (const float*)d_in[5];
  const float* lin1_ws = (const float*)d_in[6];
  const float* lin1_wv = (const float*)d_in[7];
  const float* fc_w1   = (const float*)d_in[8];
  const float* fc_w2   = (const float*)d_in[9];
  const float* sc_ws   = (const float*)d_in[10];
  const float* sc_wv   = (const float*)d_in[11];
  const float* lin2_ws = (const float*)d_in[12];
  const float* lin2_wv = (const float*)d_in[13];
  float* out = (float*)d_out;

  float* ws    = (float*)d_ws;
  float* h_s   = ws;                            // N*64
  float* h_v   = h_s + (size_t)N_NODES * 64;    // N*96
  float* agg_s = h_v + (size_t)N_NODES * 96;    // N*96
  float* agg_v = agg_s + (size_t)N_NODES * 96;  // N*96
  unsigned short* w1t = (unsigned short*)(agg_v + (size_t)N_NODES * 96); // 64*64
  unsigned short* w2t = w1t + 64 * 64;    // 224*64
  unsigned short* wst = w2t + 224 * 64;   // 96*96
  unsigned short* wvt = wst + 96 * 96;    // 32*128
  float* gate = h_s;                      // reuse h_s region after k_edge

  hipMemsetAsync(agg_s, 0, (size_t)N_NODES * 192 * sizeof(float), stream);
  k_prep<<<124, 256, 0, stream>>>(fc_w1, fc_w2, lin2_ws, lin2_wv, w1t, w2t, wst, wvt);
  k_node_hs<<<(N_NODES * 64 + 255) / 256, 256, 0, stream>>>(nf, attr, lin1_ws, h_s);
  k_node_hv<<<(N_NODES * 32 + 255) / 256, 256, 0, stream>>>(nf, attr, lin1_wv, h_v);
  k_edge<<<N_EDGES / 64, 256, 0, stream>>>(escal, eattr, esrc, edst,
                                           w1t, w2t, wst, wvt, h_s, h_v, agg_s, agg_v);
  k_fin_s<<<(N_NODES * 96 + 255) / 256, 256, 0, stream>>>(nf, attr, agg_s, sc_ws, out, gate);
  k_fin_v<<<(N_NODES * 32 + 255) / 256, 256, 0, stream>>>(nf, attr, agg_v, sc_wv, gate, out);
}